// Round 2
// baseline (269.045 us; speedup 1.0000x reference)
//
#include <hip/hip_runtime.h>
#include <math.h>

#define IMG_H 112
#define IMG_W 112
#define NB    4
#define CI    8
#define CO    16
#define EPS   1e-6f

// One thread per output pixel; computes all 16 output channels.
// Weights (1152x8) + bias (1152) are read via wave-uniform addresses ->
// compiler emits scalar loads (SMEM pipe), keeping the VALU pipe for the
// 11520 FMAs/pixel that dominate.
// kh/kw loops pinned to no-unroll to keep code size / compile time sane.
__global__ __launch_bounds__(64) void coda_kernel(
    const float* __restrict__ in, const float* __restrict__ wp,
    const float* __restrict__ bp, float* __restrict__ out)
{
  const int idx = blockIdx.x * 64 + threadIdx.x;
  const int w = idx % IMG_W;
  const int h = (idx / IMG_W) % IMG_H;
  const int b = idx / (IMG_W * IMG_H);

  const float* __restrict__ inb = in + (size_t)b * CI * IMG_H * IMG_W;

  // center pixel across channels
  float x[CI];
#pragma unroll
  for (int c = 0; c < CI; ++c)
    x[c] = inb[c * IMG_H * IMG_W + h * IMG_W + w];

  float acc[CO];
  float n2[CO];
#pragma unroll
  for (int co = 0; co < CO; ++co) { acc[co] = 0.f; n2[co] = 0.f; }

#pragma unroll 1
  for (int kh = 0; kh < 3; ++kh) {
    const int hh = h + kh - 1;
    const bool hin = ((unsigned)hh < IMG_H);
#pragma unroll 1
    for (int kw = 0; kw < 3; ++kw) {
      const int ww2 = w + kw - 1;
      const bool ok = hin && ((unsigned)ww2 < IMG_W);
      const int sbase = hh * IMG_W + ww2;  // only used when ok
#pragma unroll
      for (int c = 0; c < CI; ++c) {
        const float pv = ok ? inb[c * IMG_H * IMG_W + sbase] : 0.f;
        // patch index: channel-major, then kh, kw (jax dilated_patches order)
        const int p = c * 9 + kh * 3 + kw;
        const float* __restrict__ wrow = wp + (size_t)p * CO * CI;  // 128 floats, uniform
        const float* __restrict__ brow = bp + p * CO;               // 16 floats, uniform
#pragma unroll
        for (int co = 0; co < CO; ++co) {
          float Wv = brow[co];
#pragma unroll
          for (int cc = 0; cc < CI; ++cc)
            Wv = fmaf(wrow[co * CI + cc], x[cc], Wv);
          acc[co] = fmaf(pv, Wv, acc[co]);
          n2[co]  = fmaf(Wv, Wv, n2[co]);
        }
      }
    }
  }

  float* __restrict__ outp = out + (size_t)b * CO * IMG_H * IMG_W + h * IMG_W + w;
#pragma unroll
  for (int co = 0; co < CO; ++co)
    outp[co * IMG_H * IMG_W] = acc[co] / (sqrtf(n2[co]) + EPS);
}

extern "C" void kernel_launch(void* const* d_in, const int* in_sizes, int n_in,
                              void* d_out, int out_size, void* d_ws, size_t ws_size,
                              hipStream_t stream) {
  const float* in = (const float*)d_in[0];
  const float* wp = (const float*)d_in[1];
  const float* bp = (const float*)d_in[2];
  float* out = (float*)d_out;

  const int n_pix = NB * IMG_H * IMG_W;          // 200704
  coda_kernel<<<dim3(n_pix / 64), dim3(64), 0, stream>>>(in, wp, bp, out);
}

// Round 5
// 105.320 us; speedup vs baseline: 2.5546x; 2.5546x over previous
//
#include <hip/hip_runtime.h>
#include <math.h>

#define IMG_W 112
#define HW    12544          // 112*112
#define CI    8
#define CO    16
#define EPS   1e-6f
#define T     4              // pixel slots per thread

// Lane layout: co = lane>>2 (16 output channels), ps = lane&3 (4 pixel slots).
// Each wave handles 16 consecutive pixels (4 slots x T groups), all 16 co.
// Total pixels = 4*112*112 = 50176 -> 3136 waves -> 784 blocks of 256.
// (Rounds 3/4 launched 4x too many waves -> OOB writes -> core dump.)
// Weights are per-lane float4 VMEM loads (quads share an address -> L1
// broadcast). Boundary handling is branch-free and always-in-bounds.
__global__ __launch_bounds__(256) void coda_kernel(
    const float* __restrict__ in, const float* __restrict__ wp,
    const float* __restrict__ bp, float* __restrict__ out)
{
  const int tid  = blockIdx.x * 256 + threadIdx.x;
  const int wave = tid >> 6;
  const int lane = threadIdx.x & 63;
  const int co   = lane >> 2;
  const int ps   = lane & 3;

  const int base = wave * 16;            // first pixel index of this wave

  float x[T][CI];
  float acc[T], n2[T];
  int   h_[T], w_[T];
  long  inoff[T], outoff[T];

#pragma unroll
  for (int t = 0; t < T; ++t) {
    const int n = base + 4 * t + ps;     // pixel index in [0, 50176)
    const int b = n / HW;                // batch in [0, 4)
    const int r = n - b * HW;
    const int h = r / IMG_W;
    const int w = r - h * IMG_W;
    h_[t] = h; w_[t] = w;
    inoff[t]  = (long)b * CI * HW + r;         // in + inoff + c*HW = in[b,c,h,w]
    outoff[t] = (long)b * CO * HW + (long)co * HW + r;
    const float* __restrict__ p = in + inoff[t];
#pragma unroll
    for (int c = 0; c < CI; ++c) x[t][c] = p[c * HW];
    acc[t] = 0.f; n2[t] = 0.f;
  }

#pragma unroll 1
  for (int kh = 0; kh < 3; ++kh) {
#pragma unroll 1
    for (int kw = 0; kw < 3; ++kw) {
      const int q  = kh * 3 + kw;
      const int dq = (kh - 1) * IMG_W + (kw - 1);   // patch offset delta
      int   d_[T];
      float m_[T];
#pragma unroll
      for (int t = 0; t < T; ++t) {
        const bool ok = ((unsigned)(h_[t] + kh - 1) < 112u) &&
                        ((unsigned)(w_[t] + kw - 1) < 112u);
        d_[t] = ok ? dq : 0;        // always-in-bounds offset
        m_[t] = ok ? 1.f : 0.f;     // mask folded into patch value
      }

#pragma unroll
      for (int c = 0; c < CI; ++c) {
        const int row = (c * 9 + q) * CO + co;       // o = p*16 + co
        const float* __restrict__ wr = wp + (long)row * CI;
        const float4 wa = *(const float4*)wr;        // 32B-aligned rows
        const float4 wb = *(const float4*)(wr + 4);
        const float  bq = bp[row];
#pragma unroll
        for (int t = 0; t < T; ++t) {
          float Wv = bq;
          Wv = fmaf(wa.x, x[t][0], Wv);
          Wv = fmaf(wa.y, x[t][1], Wv);
          Wv = fmaf(wa.z, x[t][2], Wv);
          Wv = fmaf(wa.w, x[t][3], Wv);
          Wv = fmaf(wb.x, x[t][4], Wv);
          Wv = fmaf(wb.y, x[t][5], Wv);
          Wv = fmaf(wb.z, x[t][6], Wv);
          Wv = fmaf(wb.w, x[t][7], Wv);
          const float pv = m_[t] * in[inoff[t] + (long)c * HW + d_[t]];
          acc[t] = fmaf(pv, Wv, acc[t]);
          n2[t]  = fmaf(Wv, Wv, n2[t]);
        }
      }
    }
  }

#pragma unroll
  for (int t = 0; t < T; ++t)
    out[outoff[t]] = acc[t] / (sqrtf(n2[t]) + EPS);
}

extern "C" void kernel_launch(void* const* d_in, const int* in_sizes, int n_in,
                              void* d_out, int out_size, void* d_ws, size_t ws_size,
                              hipStream_t stream) {
  const float* in = (const float*)d_in[0];
  const float* wp = (const float*)d_in[1];
  const float* bp = (const float*)d_in[2];
  float* out = (float*)d_out;

  // 50176 pixels / 16 pixels-per-wave = 3136 waves = 784 blocks of 4 waves
  coda_kernel<<<dim3(784), dim3(256), 0, stream>>>(in, wp, bp, out);
}

// Round 6
// 85.285 us; speedup vs baseline: 3.1546x; 1.2349x over previous
//
#include <hip/hip_runtime.h>
#include <math.h>

#define IMG_W 112
#define HW    12544          // 112*112
#define CI    8
#define CO    16
#define NROW  1152           // 72 patch positions * 16 co
#define EPS   1e-6f

// Lane layout: co = lane>>2, ps = lane&3. Each thread computes 1 output
// channel for 4 CONSECUTIVE pixels (n0 = wave*16 + ps*4), so patch loads are
// one aligned float4 + 2 clamped scalars per (kh,c) and the store is float4.
// Weights (36KB) + bias (4.5KB) staged in LDS once per block: the table
// doesn't fit L1 (32KB), so round-5's per-lane global weight loads all missed
// to L2 (~200cyc) -> latency-bound at VALUBusy=23%. LDS fixes that.
// Boundary masks fold into the 6-element row segment v[i] once per (kh,c):
// patch column for v[i] is w0+i-1 regardless of the (pixel, kw) split.
__global__ __launch_bounds__(256) void coda_kernel(
    const float* __restrict__ in, const float* __restrict__ wp,
    const float* __restrict__ bp, float* __restrict__ out)
{
  __shared__ float sw[NROW][CI];   // 36864 B
  __shared__ float sb[NROW];       //  4608 B

  {  // cooperative stage: wp = 2304 float4, bp = 288 float4
    const float4* __restrict__ w4 = (const float4*)wp;
    float4* s4 = (float4*)&sw[0][0];
#pragma unroll
    for (int i = threadIdx.x; i < 2304; i += 256) s4[i] = w4[i];
    const float4* __restrict__ b4 = (const float4*)bp;
    float4* sb4 = (float4*)sb;
#pragma unroll
    for (int i = threadIdx.x; i < 288; i += 256) sb4[i] = b4[i];
  }
  __syncthreads();

  const int wave = blockIdx.x * 4 + (threadIdx.x >> 6);
  const int lane = threadIdx.x & 63;
  const int co   = lane >> 2;
  const int ps   = lane & 3;

  const int n0 = wave * 16 + ps * 4;   // 4 consecutive pixels, same row (112%4==0)
  const int b  = n0 / HW;
  const int r  = n0 - b * HW;
  const int h  = r / IMG_W;
  const int w0 = r - h * IMG_W;

  const float* __restrict__ inb = in + b * CI * HW;

  // center values x[j][c] for the 4 pixels
  float x[4][CI];
#pragma unroll
  for (int c = 0; c < CI; ++c) {
    const float4 f = *(const float4*)(inb + c * HW + r);
    x[0][c] = f.x; x[1][c] = f.y; x[2][c] = f.z; x[3][c] = f.w;
  }

  float acc[4] = {0.f, 0.f, 0.f, 0.f};
  float n2[4]  = {0.f, 0.f, 0.f, 0.f};

  // column masks: v[i] holds patch column w0+i-1
  float cmask[6];
#pragma unroll
  for (int i = 0; i < 6; ++i)
    cmask[i] = ((unsigned)(w0 + i - 1) < 112u) ? 1.f : 0.f;
  const int lw = (w0 == 0) ? 0 : (w0 - 1);          // clamped, masked anyway
  const int rw = (w0 + 4 > 111) ? 111 : (w0 + 4);

#pragma unroll 1
  for (int kh = 0; kh < 3; ++kh) {
    const int hh = h + kh - 1;
    const float rmask = ((unsigned)hh < 112u) ? 1.f : 0.f;
    const int hc = (hh < 0) ? 0 : (hh > 111 ? 111 : hh);
    const int rowbase = hc * IMG_W;

    float vm[6];
#pragma unroll
    for (int i = 0; i < 6; ++i) vm[i] = rmask * cmask[i];

#pragma unroll
    for (int c = 0; c < CI; ++c) {
      const float* __restrict__ rp = inb + c * HW + rowbase;
      const float4 f = *(const float4*)(rp + w0);   // aligned, in-bounds
      float v[6];
      v[0] = rp[lw] * vm[0];
      v[1] = f.x * vm[1];
      v[2] = f.y * vm[2];
      v[3] = f.z * vm[3];
      v[4] = f.w * vm[4];
      v[5] = rp[rw] * vm[5];

      const int pbase = (c * 9 + kh * 3) * CO + co;
#pragma unroll
      for (int kw = 0; kw < 3; ++kw) {
        const int row = pbase + kw * CO;
        const float4 wa = *(const float4*)&sw[row][0];
        const float4 wb = *(const float4*)&sw[row][4];
        const float  bq = sb[row];
#pragma unroll
        for (int j = 0; j < 4; ++j) {
          float Wv = bq;
          Wv = fmaf(wa.x, x[j][0], Wv);
          Wv = fmaf(wa.y, x[j][1], Wv);
          Wv = fmaf(wa.z, x[j][2], Wv);
          Wv = fmaf(wa.w, x[j][3], Wv);
          Wv = fmaf(wb.x, x[j][4], Wv);
          Wv = fmaf(wb.y, x[j][5], Wv);
          Wv = fmaf(wb.z, x[j][6], Wv);
          Wv = fmaf(wb.w, x[j][7], Wv);
          acc[j] = fmaf(v[j + kw], Wv, acc[j]);
          n2[j]  = fmaf(Wv, Wv, n2[j]);
        }
      }
    }
  }

  float4 o;
  o.x = acc[0] / (sqrtf(n2[0]) + EPS);
  o.y = acc[1] / (sqrtf(n2[1]) + EPS);
  o.z = acc[2] / (sqrtf(n2[2]) + EPS);
  o.w = acc[3] / (sqrtf(n2[3]) + EPS);
  *(float4*)(out + (long)b * CO * HW + (long)co * HW + r) = o;
}

extern "C" void kernel_launch(void* const* d_in, const int* in_sizes, int n_in,
                              void* d_out, int out_size, void* d_ws, size_t ws_size,
                              hipStream_t stream) {
  const float* in = (const float*)d_in[0];
  const float* wp = (const float*)d_in[1];
  const float* bp = (const float*)d_in[2];
  float* out = (float*)d_out;

  // 50176 pixels / 16 pixels-per-wave = 3136 waves = 784 blocks of 4 waves
  coda_kernel<<<dim3(784), dim3(256), 0, stream>>>(in, wp, bp, out);
}

// Round 7
// 78.523 us; speedup vs baseline: 3.4263x; 1.0861x over previous
//
#include <hip/hip_runtime.h>
#include <math.h>

#define IMG_W 112
#define HW    12544          // 112*112
#define CI    8
#define CO    16
#define NP    72             // patch positions
#define EPS   1e-6f

typedef __attribute__((ext_vector_type(8))) short short8;  // 8 bf16 = 4 VGPRs
typedef __attribute__((ext_vector_type(4))) float f32x4;

static __device__ inline short f2bf(float f) {  // RNE float->bf16 bits
  unsigned u = __float_as_uint(f);
  return (short)((u + 0x7FFFu + ((u >> 16) & 1u)) >> 16);
}

// Per wave: 16 consecutive pixels (one image row chunk; 112%16==0), all 16 co.
// raw[p*16+co, n] via one mfma_f32_16x16x32_bf16 per p: M=co(16), N=pixel(16),
// K: slots 0..7 = c (W·x), slot 8 = bias (B row = 1.0), slots 9..31 = 0.
// C/D layout: col=lane&15=n, row=quad*4+reg=co -> patch[p,n] is a per-lane
// scalar, acc folds with 8 VALU FMAs per p. A-fragments pre-swizzled in LDS
// in fragment order (conflict-free b128 reads). Input neighborhood staged as
// flattened [c][290] with index clamp; borders killed by per-lane masks.
__global__ __launch_bounds__(256) void coda_mfma(
    const float* __restrict__ in, const float* __restrict__ wp,
    const float* __restrict__ bp, float* __restrict__ out)
{
  __shared__ short sA[NP][32][8];   // 36864B, A-frag order: [p][quad*16+m][j]
  __shared__ float sIn[CI][290];    //  9280B
  __shared__ short sZ[16];          //    32B zero frag for quads 2,3

  const int tid = threadIdx.x;
  const int b   = blockIdx.x / 196;            // 196 blocks (64 px) per image
  const int r0  = (blockIdx.x - b * 196) * 64; // first flat pixel of block
  const float* __restrict__ inb = in + b * CI * HW;

  // ---- stage A-fragments (bf16 weights + bias-in-K) ----
  for (int idx = tid; idx < NP * 32; idx += 256) {
    const int p = idx >> 5, l = idx & 31, q = l >> 4, m = l & 15;
    const int row = p * 16 + m;                // o = p*16 + co
    short8 v = {0, 0, 0, 0, 0, 0, 0, 0};
    if (q == 0) {
      const float* wr = wp + row * CI;
#pragma unroll
      for (int j = 0; j < 8; ++j) v[j] = f2bf(wr[j]);
    } else {
      v[0] = f2bf(bp[row]);                    // K slot 8 = bias
    }
    *(short8*)&sA[p][l][0] = v;
  }
  if (tid < 16) sZ[tid] = 0;
  // ---- stage input neighborhood: flat offsets [r0-113, r0+176] clamped ----
  for (int k = tid; k < CI * 290; k += 256) {
    const int c = k / 290;
    const int i = k - c * 290;
    int g = r0 - 113 + i;
    g = (g < 0) ? 0 : (g > HW - 1 ? HW - 1 : g);
    sIn[c][i] = inb[c * HW + g];
  }
  __syncthreads();

  const int wib  = tid >> 6;
  const int lane = tid & 63;
  const int ln   = lane & 15;                  // pixel slot = A row m = B col n
  const int quad = lane >> 4;
  const int rwav = r0 + wib * 16;
  const int h    = rwav / IMG_W;
  const int wl   = (rwav - h * IMG_W) + ln;    // this lane's pixel column
  const int off  = wib * 16 + ln + 113;        // center index into sIn rows

  // border masks per q = kh*3+kw
  float vm[9];
#pragma unroll
  for (int q = 0; q < 9; ++q) {
    const int kh = q / 3, kw = q % 3;
    const bool ok = ((unsigned)(h + kh - 1) < 112u) &&
                    ((unsigned)(wl + kw - 1) < 112u);
    vm[q] = ok ? 1.f : 0.f;
  }

  // B fragment: quad0 = x[c,n] bf16; quad1 = {1,0,...}; quads 2,3 = 0
  short8 bf = {0, 0, 0, 0, 0, 0, 0, 0};
#pragma unroll
  for (int j = 0; j < 8; ++j) {
    const short bv = f2bf(sIn[j][off]);        // all lanes read valid addr
    bf[j] = (quad == 0) ? bv : ((quad == 1 && j == 0) ? (short)0x3F80 : (short)0);
  }

  float acc[4] = {0.f, 0.f, 0.f, 0.f};
  float n2[4]  = {0.f, 0.f, 0.f, 0.f};
  const bool qlo = (quad < 2);

#pragma unroll 1
  for (int c = 0; c < CI; ++c) {
    const float* __restrict__ sc = &sIn[c][off];
#pragma unroll
    for (int q = 0; q < 9; ++q) {
      static const int dq[9] = {-113, -112, -111, -1, 0, 1, 111, 112, 113};
      const int p = c * 9 + q;
      const short* ap = qlo ? &sA[p][quad * 16 + ln][0] : &sZ[0];
      const short8 af = *(const short8*)ap;
      const float pv = vm[q] * sc[dq[q]];
      const f32x4 zc = {0.f, 0.f, 0.f, 0.f};
      const f32x4 d = __builtin_amdgcn_mfma_f32_16x16x32_bf16(af, bf, zc, 0, 0, 0);
#pragma unroll
      for (int i = 0; i < 4; ++i) {
        acc[i] = fmaf(pv, d[i], acc[i]);
        n2[i]  = fmaf(d[i], d[i], n2[i]);
      }
    }
  }

  // store: co = quad*4 + i, pixel = rwav + ln (16-lane coalesced per co)
  float* __restrict__ ob = out + (long)b * CO * HW + rwav + ln;
#pragma unroll
  for (int i = 0; i < 4; ++i) {
    const int co = quad * 4 + i;
    ob[(long)co * HW] = acc[i] / (sqrtf(n2[i]) + EPS);
  }
}

extern "C" void kernel_launch(void* const* d_in, const int* in_sizes, int n_in,
                              void* d_out, int out_size, void* d_ws, size_t ws_size,
                              hipStream_t stream) {
  const float* in = (const float*)d_in[0];
  const float* wp = (const float*)d_in[1];
  const float* bp = (const float*)d_in[2];
  float* out = (float*)d_out;

  // 50176 pixels / 64 per block = 784 blocks of 4 waves
  coda_mfma<<<dim3(784), dim3(256), 0, stream>>>(in, wp, bp, out);
}

// Round 8
// 72.108 us; speedup vs baseline: 3.7311x; 1.0890x over previous
//
#include <hip/hip_runtime.h>
#include <math.h>

#define IMG_W 112
#define HW    12544          // 112*112
#define CI    8
#define CO    16
#define NP    72             // patch positions
#define EPS   1e-6f

typedef __attribute__((ext_vector_type(8))) short short8;  // 8 bf16 = 4 VGPRs
typedef __attribute__((ext_vector_type(4))) float f32x4;

static __device__ inline short f2bf(float f) {  // RNE float->bf16 bits
  unsigned u = __float_as_uint(f);
  return (short)((u + 0x7FFFu + ((u >> 16) & 1u)) >> 16);
}

static constexpr int DQ[9] = {-113, -112, -111, -1, 0, 1, 111, 112, 113};

// Round 8: p-split for TLP. 512-thread blocks (8 waves) on 64 pixels:
// wave = (half, group); group owns 16 consecutive pixels, half owns channels
// c in [4*half, 4*half+4) -> 36 of the 72 MFMAs. 6272 waves total (2x round
// 7's 3136, which capped occupancy at 3 waves/SIMD). The 36-iteration loop is
// fully unrolled so all ds_read_b128 A-frags issue ahead of the MFMA chain.
// acc/n2 are linear in p: halves combine via LDS partials, reusing the input
// staging buffer (dead after the main loop) to keep LDS at 46KB = 3 blocks/CU.
__global__ __launch_bounds__(512) void coda_mfma(
    const float* __restrict__ in, const float* __restrict__ wp,
    const float* __restrict__ bp, float* __restrict__ out)
{
  __shared__ short sA[NP][32][8];   // 36864B, A-frag order: [p][quad*16+m][j]
  __shared__ float sBuf[CI * 290];  //  9280B: input stage, then 2048-f partials
  __shared__ short sZ[16];          //    32B zero frag for quads 2,3

  const int tid = threadIdx.x;
  const int b   = blockIdx.x / 196;            // 196 blocks (64 px) per image
  const int r0  = (blockIdx.x - b * 196) * 64; // first flat pixel of block
  const float* __restrict__ inb = in + b * CI * HW;

  // ---- stage A-fragments (bf16 weights + bias in K-slot 8) ----
  for (int idx = tid; idx < NP * 32; idx += 512) {
    const int p = idx >> 5, l = idx & 31, q = l >> 4, m = l & 15;
    const int row = p * 16 + m;                // o = p*16 + co
    short8 v = {0, 0, 0, 0, 0, 0, 0, 0};
    if (q == 0) {
      const float* wr = wp + row * CI;
#pragma unroll
      for (int j = 0; j < 8; ++j) v[j] = f2bf(wr[j]);
    } else {
      v[0] = f2bf(bp[row]);                    // K slot 8 = bias
    }
    *(short8*)&sA[p][l][0] = v;
  }
  if (tid < 16) sZ[tid] = 0;
  // ---- stage input neighborhood: flat offsets [r0-113, r0+176] clamped ----
  for (int k = tid; k < CI * 290; k += 512) {
    const int c = k / 290;
    const int i = k - c * 290;
    int gg = r0 - 113 + i;
    gg = (gg < 0) ? 0 : (gg > HW - 1 ? HW - 1 : gg);
    sBuf[k] = inb[c * HW + gg];
  }
  __syncthreads();

  const int wave = tid >> 6;
  const int lane = tid & 63;
  const int g    = wave & 3;                   // pixel group
  const int half = wave >> 2;                  // channel half
  const int ln   = lane & 15;                  // pixel slot = A row m = B col n
  const int quad = lane >> 4;
  const int rwav = r0 + g * 16;
  const int h    = rwav / IMG_W;
  const int wl   = (rwav - h * IMG_W) + ln;    // this lane's pixel column
  const int off  = g * 16 + ln + 113;          // center index into sBuf rows

  // border masks per q = kh*3+kw
  float vm[9];
#pragma unroll
  for (int q = 0; q < 9; ++q) {
    const int kh = q / 3, kw = q % 3;
    const bool ok = ((unsigned)(h + kh - 1) < 112u) &&
                    ((unsigned)(wl + kw - 1) < 112u);
    vm[q] = ok ? 1.f : 0.f;
  }

  // B fragment: quad0 = x[c,n] bf16 (all 8 channels); quad1 = e0 (bias row)
  short8 bf = {0, 0, 0, 0, 0, 0, 0, 0};
#pragma unroll
  for (int j = 0; j < 8; ++j) {
    const short bv = f2bf(sBuf[j * 290 + off]);
    bf[j] = (quad == 0) ? bv : ((quad == 1 && j == 0) ? (short)0x3F80 : (short)0);
  }

  float acc[4] = {0.f, 0.f, 0.f, 0.f};
  float n2[4]  = {0.f, 0.f, 0.f, 0.f};
  const bool qlo = (quad < 2);
  const int  c0  = half * 4;

#pragma unroll
  for (int cc = 0; cc < 4; ++cc) {
    const int c = c0 + cc;
    const float* __restrict__ sc = &sBuf[c * 290 + off];
#pragma unroll
    for (int q = 0; q < 9; ++q) {
      const int p = c * 9 + q;
      const short* ap = qlo ? &sA[p][quad * 16 + ln][0] : &sZ[0];
      const short8 af = *(const short8*)ap;
      const float pv = vm[q] * sc[DQ[q]];
      const f32x4 zc = {0.f, 0.f, 0.f, 0.f};
      const f32x4 d = __builtin_amdgcn_mfma_f32_16x16x32_bf16(af, bf, zc, 0, 0, 0);
#pragma unroll
      for (int i = 0; i < 4; ++i) {
        acc[i] = fmaf(pv, d[i], acc[i]);
        n2[i]  = fmaf(d[i], d[i], n2[i]);
      }
    }
  }

  // ---- combine halves via LDS (sBuf is dead now), half 0 stores ----
  __syncthreads();
  if (half == 1) {
#pragma unroll
    for (int i = 0; i < 4; ++i) {
      sBuf[i * 256 + g * 64 + lane]       = acc[i];   // conflict-free b32
      sBuf[(i + 4) * 256 + g * 64 + lane] = n2[i];
    }
  }
  __syncthreads();
  if (half == 0) {
    float* __restrict__ ob = out + (long)b * CO * HW + rwav + ln;
#pragma unroll
    for (int i = 0; i < 4; ++i) {
      const float a2 = acc[i] + sBuf[i * 256 + g * 64 + lane];
      const float s2 = n2[i] + sBuf[(i + 4) * 256 + g * 64 + lane];
      const int co = quad * 4 + i;
      ob[(long)co * HW] = a2 / (sqrtf(s2) + EPS);
    }
  }
}

extern "C" void kernel_launch(void* const* d_in, const int* in_sizes, int n_in,
                              void* d_out, int out_size, void* d_ws, size_t ws_size,
                              hipStream_t stream) {
  const float* in = (const float*)d_in[0];
  const float* wp = (const float*)d_in[1];
  const float* bp = (const float*)d_in[2];
  float* out = (float*)d_out;

  // 50176 pixels / 64 per block = 784 blocks of 8 waves (p-split pairs)
  coda_mfma<<<dim3(784), dim3(512), 0, stream>>>(in, wp, bp, out);
}